// Round 6
// baseline (264.981 us; speedup 1.0000x reference)
//
#include <hip/hip_runtime.h>

typedef float f2 __attribute__((ext_vector_type(2)));
typedef float f4 __attribute__((ext_vector_type(4)));

static constexpr int Hh = 256, Ww = 256, HW = Hh * Ww;
static constexpr int PLANES = 512;            // N*C
static constexpr int STRIPS = 8;
static constexpr int ROWS   = Hh / STRIPS;    // 32
static constexpr int DEPTH  = 10;
static constexpr int RB     = 4;              // rows advanced per sweep step
static constexpr int NSTEP  = (ROWS + 2 * DEPTH) / RB;   // 13

#if __has_builtin(__builtin_amdgcn_exp2f)
#define EXP2F(x) __builtin_amdgcn_exp2f(x)
#else
#define EXP2F(x) __expf((x) * 0.6931471805599453f)
#endif
#if __has_builtin(__builtin_amdgcn_logf)
#define LOG2F(x) __builtin_amdgcn_logf(x)
#else
#define LOG2F(x) (__logf(x) * 1.4426950408889634f)
#endif

static constexpr float LN2 = 0.6931471805599453f;
static constexpr float L2E = 1.4426950408889634f;
static constexpr float AZS = 10.0f * L2E;     // BETA folded into exp2 arg

__device__ __forceinline__ f2 pkfma(f2 a, f2 b, f2 c) {
#if __has_builtin(__builtin_elementwise_fma)
    return __builtin_elementwise_fma(a, b, c);
#else
    return f2{fmaf(a.x, b.x, c.x), fmaf(a.y, b.y, c.y)};
#endif
}
__device__ __forceinline__ f2 pkmax(f2 a, f2 b) {
#if __has_builtin(__builtin_elementwise_max)
    return __builtin_elementwise_max(a, b);
#else
    return f2{fmaxf(a.x, b.x), fmaxf(a.y, b.y)};
#endif
}

// softplus(10z) pieces in base 2, z unscaled:
//   lg = log2(1 + 2^(-|z|*10*log2e)),  mz = max(z,0)
__device__ __forceinline__ void sp_parts(f2 z, f2& lg, f2& mz) {
    f2 az = pkmax(z, -z);
    f2 a  = az * AZS;
    f2 p;
    p.x = EXP2F(-a.x);
    p.y = EXP2F(-a.y);
    f2 op = p + 1.0f;
    lg.x = LOG2F(op.x);
    lg.y = LOG2F(op.y);
    mz = pkmax(z, f2{0.f, 0.f});
}
// t = 1 - 2*slrelu(z) = 1 - 0.4 z - 1.6 mz - 0.16*ln2 * lg
__device__ __forceinline__ f2 tval(f2 z) {
    f2 lg, mz;
    sp_parts(z, lg, mz);
    return pkfma(f2{-0.16f * LN2, -0.16f * LN2}, lg,
           pkfma(f2{-1.6f, -1.6f}, mz,
           pkfma(f2{-0.4f, -0.4f}, z, f2{1.f, 1.f})));
}
// u = slrelu(z) = 0.2 z + 0.8 mz + 0.08*ln2 * lg
__device__ __forceinline__ f2 uval(f2 z) {
    f2 lg, mz;
    sp_parts(z, lg, mz);
    return pkfma(f2{0.08f * LN2, 0.08f * LN2}, lg,
           pkfma(f2{0.8f, 0.8f}, mz, f2{0.2f, 0.2f} * z));
}

__global__ __launch_bounds__(64, 4)
void k_fused(const float* __restrict__ o, const float* __restrict__ sigma,
             const float* __restrict__ lam, float* __restrict__ out) {
    const int lane  = threadIdx.x;
    const int bid   = blockIdx.x;
    const int plane = bid >> 3;               // 512 planes
    const int strip = bid & 7;
    const int y0    = strip * ROWS;
    const int ch    = plane & 63;

    float s   = fmaxf(sigma[ch], 1e-6f);
    float eg  = __expf(-1.0f / (2.0f * s * s));
    float inv = 1.0f / (1.0f + 2.0f * eg);
    const float w0s = eg * inv, w1s = inv, l = lam[0];
    const f2 w0 = f2{w0s, w0s}, w1 = f2{w1s, w1s};
    const f2 W0 = f2{-l * w0s, -l * w0s};     // vertical taps, -lam folded
    const f2 W1 = f2{-l * w1s, -l * w1s};
    const f2 zero = f2{0.f, 0.f};

    const float* op_lane = o   + plane * HW + lane * 4;
    float*       up_lane = out + plane * HW + lane * 4;
    const int a_up = ((lane + 63) & 63) << 2;
    const int a_dn = ((lane + 1)  & 63) << 2;

    // hA carries (row r-1 of each stage's h) in LDS: wave-private, no barriers
    __shared__ f4 hcA[DEPTH][64];
    // hB carries (row r of each stage's h) in registers
    f2 hB[DEPTH][2];
#pragma unroll
    for (int k = 0; k < DEPTH; ++k) {
        hcA[k][lane] = f4{0.f, 0.f, 0.f, 0.f};
        hB[k][0] = zero;
        hB[k][1] = zero;
    }

    // clamped o-row load into a 4-slot rolling window (slot = rel & 3)
    auto oload = [&](int r) -> void {};  // (placeholder to keep structure clear)

#pragma unroll 1
    for (int j = 0; j < NSTEP; ++j) {
        const int yS = y0 - DEPTH + RB * j;   // fresh stage-0 rows yS..yS+3

        // rolling o window: slot = (rel)&3, rel = row - (yS - DEPTH)
        f2 ow[4][2];
#pragma unroll
        for (int m = 0; m < RB; ++m) {        // rel = 10+m -> rows yS..yS+3
            int r = yS + m;
            r = r < 0 ? 0 : (r > 255 ? 255 : r);
            f4 v = *reinterpret_cast<const f4*>(op_lane + r * Ww);
            ow[(DEPTH + m) & 3][0] = f2{v.x, v.y};
            ow[(DEPTH + m) & 3][1] = f2{v.z, v.w};
        }

        // ---- stage 0: t0 rows yS..yS+3 ----
        f2 tin[RB][2];
#pragma unroll
        for (int m = 0; m < RB; ++m) {
            const bool rv = (unsigned)(yS + m) < 256u;
#pragma unroll
            for (int i = 0; i < 2; ++i) {
                f2 t = tval(ow[(DEPTH + m) & 3][i]);
                tin[m][i] = rv ? t : zero;
            }
        }

        // ---- stages 1..10 ----
#pragma unroll
        for (int k = 1; k <= DEPTH; ++k) {
            // slide o window: new row rel = 10-k (row yS-k), overwrites rel 14-k
            {
                int r = yS - k;
                r = r < 0 ? 0 : (r > 255 ? 255 : r);
                f4 v = *reinterpret_cast<const f4*>(op_lane + r * Ww);
                ow[(DEPTH - k) & 3][0] = f2{v.x, v.y};
                ow[(DEPTH - k) & 3][1] = f2{v.z, v.w};
            }
            // hA from LDS (issue early; consumed after hconv)
            const f4 cA = hcA[k - 1][lane];

            // horizontal conv of the 4 incoming t rows -> hn[m] = h(yS-k+1+m)
            f2 hn[RB][2];
#pragma unroll
            for (int m = 0; m < RB; ++m) {
                const f2 t0 = tin[m][0], t1 = tin[m][1];
                float lft = __int_as_float(__builtin_amdgcn_ds_bpermute(a_up, __float_as_int(t1.y)));
                float rgt = __int_as_float(__builtin_amdgcn_ds_bpermute(a_dn, __float_as_int(t0.x)));
                lft = (lane == 0)  ? 0.f : lft;
                rgt = (lane == 63) ? 0.f : rgt;
                f2 tl0 = {lft,  t0.x};
                f2 mid = {t0.y, t1.x};
                f2 tr1 = {t1.y, rgt};
                hn[m][0] = pkfma(w1, t0, w0 * (tl0 + mid));
                hn[m][1] = pkfma(w1, t1, w0 * (mid + tr1));
            }

            const f2 hA2[2] = {f2{cA.x, cA.y}, f2{cA.z, cA.w}};

#pragma unroll
            for (int m = 0; m < RB; ++m) {
                const int r = yS - k + m;
                const bool rv = (unsigned)r < 256u;
#pragma unroll
                for (int i = 0; i < 2; ++i) {
                    f2 h_im1 = (m == 0) ? hA2[i] : (m == 1) ? hB[k - 1][i] : hn[m - 2][i];
                    f2 h_i   = (m == 0) ? hB[k - 1][i] : hn[m - 1][i];
                    // z = o[r] - lam*q  (BETA folded into tval/uval)
                    f2 z = pkfma(W0, h_im1 + hn[m][i],
                           pkfma(W1, h_i, ow[(DEPTH - k + m) & 3][i]));
                    if (k < DEPTH) {
                        f2 t = tval(z);
                        tin[m][i] = rv ? t : zero;
                    } else {
                        tin[m][i] = uval(z);       // reuse tin as u output
                    }
                }
            }

            // carries for next step: hA <- h(yS-k+3)=hn[2], hB <- hn[3]
            hcA[k - 1][lane] = f4{hn[2][0].x, hn[2][0].y, hn[2][1].x, hn[2][1].y};
            hB[k - 1][0] = hn[3][0];
            hB[k - 1][1] = hn[3][1];
        }

        // ---- store u rows r = yS-10+m inside this strip ----
#pragma unroll
        for (int m = 0; m < RB; ++m) {
            const int r = yS - DEPTH + m;
            if (r >= y0 && r < y0 + ROWS) {
                f4 v;
                v.x = tin[m][0].x; v.y = tin[m][0].y;
                v.z = tin[m][1].x; v.w = tin[m][1].y;
                *reinterpret_cast<f4*>(up_lane + r * Ww) = v;
            }
        }
    }
}

extern "C" void kernel_launch(void* const* d_in, const int* in_sizes, int n_in,
                              void* d_out, int out_size, void* d_ws, size_t ws_size,
                              hipStream_t stream) {
    (void)in_sizes; (void)n_in; (void)out_size; (void)d_ws; (void)ws_size;
    const float* o     = (const float*)d_in[0];
    const float* sigma = (const float*)d_in[1];
    const float* lam   = (const float*)d_in[2];
    float* out = (float*)d_out;

    k_fused<<<PLANES * STRIPS, 64, 0, stream>>>(o, sigma, lam, out);
}

// Round 7
// 203.600 us; speedup vs baseline: 1.3015x; 1.3015x over previous
//
#include <hip/hip_runtime.h>

typedef float f2 __attribute__((ext_vector_type(2)));
typedef float f4 __attribute__((ext_vector_type(4)));

static constexpr int Hh = 256, Ww = 256, HW = Hh * Ww;
static constexpr int PLANES = 512;            // N*C
static constexpr int STRIPS = 4;
static constexpr int ROWS   = Hh / STRIPS;    // 64
static constexpr int DEPTH  = 10;
static constexpr int RB     = 4;              // rows advanced per sweep step
static constexpr int NSTEP  = (ROWS + 2 * DEPTH) / RB;   // 21

#if __has_builtin(__builtin_amdgcn_exp2f)
#define EXP2F(x) __builtin_amdgcn_exp2f(x)
#else
#define EXP2F(x) __expf((x) * 0.6931471805599453f)
#endif
#if __has_builtin(__builtin_amdgcn_logf)
#define LOG2F(x) __builtin_amdgcn_logf(x)
#else
#define LOG2F(x) (__logf(x) * 1.4426950408889634f)
#endif

static constexpr float LN2 = 0.6931471805599453f;
static constexpr float L2E = 1.4426950408889634f;
static constexpr float AZS = 10.0f * L2E;     // BETA folded into exp2 arg

__device__ __forceinline__ f2 pkfma(f2 a, f2 b, f2 c) {
#if __has_builtin(__builtin_elementwise_fma)
    return __builtin_elementwise_fma(a, b, c);
#else
    return f2{fmaf(a.x, b.x, c.x), fmaf(a.y, b.y, c.y)};
#endif
}
__device__ __forceinline__ f2 pkmax(f2 a, f2 b) {
#if __has_builtin(__builtin_elementwise_max)
    return __builtin_elementwise_max(a, b);
#else
    return f2{fmaxf(a.x, b.x), fmaxf(a.y, b.y)};
#endif
}

// softplus(10z) pieces in base 2, z unscaled:
//   lg = log2(1 + 2^(-|z|*10*log2e)),  mz = max(z,0)
__device__ __forceinline__ void sp_parts(f2 z, f2& lg, f2& mz) {
    f2 az = pkmax(z, -z);
    f2 a  = az * AZS;
    f2 p;
    p.x = EXP2F(-a.x);
    p.y = EXP2F(-a.y);
    f2 op = p + 1.0f;
    lg.x = LOG2F(op.x);
    lg.y = LOG2F(op.y);
    mz = pkmax(z, f2{0.f, 0.f});
}
// t = 1 - 2*slrelu(z) = 1 - 0.4 z - 1.6 mz - 0.16*ln2 * lg
__device__ __forceinline__ f2 tval(f2 z) {
    f2 lg, mz;
    sp_parts(z, lg, mz);
    return pkfma(f2{-0.16f * LN2, -0.16f * LN2}, lg,
           pkfma(f2{-1.6f, -1.6f}, mz,
           pkfma(f2{-0.4f, -0.4f}, z, f2{1.f, 1.f})));
}
// u = slrelu(z) = 0.2 z + 0.8 mz + 0.08*ln2 * lg
__device__ __forceinline__ f2 uval(f2 z) {
    f2 lg, mz;
    sp_parts(z, lg, mz);
    return pkfma(f2{0.08f * LN2, 0.08f * LN2}, lg,
           pkfma(f2{0.8f, 0.8f}, mz, f2{0.2f, 0.2f} * z));
}

// Pin the register allocator to exactly 2 waves/EU: budget 256 VGPRs,
// no occupancy-chasing spills (round-6 post-mortem: allocator chose 64
// VGPRs and pushed ~250 MB of scratch traffic to HBM).
__global__ __launch_bounds__(64)
__attribute__((amdgpu_waves_per_eu(2, 2)))
void k_fused(const float* __restrict__ o, const float* __restrict__ sigma,
             const float* __restrict__ lam, float* __restrict__ out) {
    const int lane  = threadIdx.x;
    const int bid   = blockIdx.x;
    const int plane = bid >> 2;               // 512 planes
    const int strip = bid & 3;
    const int y0    = strip * ROWS;
    const int ch    = plane & 63;

    float s   = fmaxf(sigma[ch], 1e-6f);
    float eg  = __expf(-1.0f / (2.0f * s * s));
    float inv = 1.0f / (1.0f + 2.0f * eg);
    const float w0s = eg * inv, w1s = inv, l = lam[0];
    const f2 w0 = f2{w0s, w0s}, w1 = f2{w1s, w1s};
    const f2 W0 = f2{-l * w0s, -l * w0s};     // vertical taps, -lam folded
    const f2 W1 = f2{-l * w1s, -l * w1s};
    const f2 zero = f2{0.f, 0.f};

    const float* op_lane = o   + plane * HW + lane * 4;
    float*       up_lane = out + plane * HW + lane * 4;
    const int a_up = ((lane + 63) & 63) << 2;
    const int a_dn = ((lane + 1)  & 63) << 2;

    // per-stage h carries: rows (r-1, r) of conv'd t_{k-1}, all in registers
    f2 hA[DEPTH][2], hB[DEPTH][2];
#pragma unroll
    for (int k = 0; k < DEPTH; ++k)
#pragma unroll
        for (int i = 0; i < 2; ++i) { hA[k][i] = zero; hB[k][i] = zero; }

#pragma unroll 1
    for (int j = 0; j < NSTEP; ++j) {
        const int yS = y0 - DEPTH + RB * j;   // fresh stage-0 rows yS..yS+3

        // ---- load o rows yS-10 .. yS+3 (14 rows), row index clamped;
        //      OOB rows yield in-bounds garbage masked before any valid use ----
        f2 orow[DEPTH + RB][2];
#pragma unroll
        for (int t = 0; t < DEPTH + RB; ++t) {
            int r = yS - DEPTH + t;
            r = r < 0 ? 0 : (r > 255 ? 255 : r);      // wave-uniform clamp
            f4 v = *reinterpret_cast<const f4*>(op_lane + r * Ww);
            orow[t][0] = f2{v.x, v.y};
            orow[t][1] = f2{v.z, v.w};
        }
        asm volatile("" ::: "memory");   // keep the load batch above the compute

        // ---- stage 0: t0 rows yS..yS+3 (orow slots 10..13) ----
        f2 tin[RB][2];
#pragma unroll
        for (int m = 0; m < RB; ++m) {
            const bool rv = (unsigned)(yS + m) < 256u;
#pragma unroll
            for (int i = 0; i < 2; ++i) {
                f2 t = tval(orow[DEPTH + m][i]);
                tin[m][i] = rv ? t : zero;
            }
        }

        // ---- stages 1..10 ----
#pragma unroll
        for (int k = 1; k <= DEPTH; ++k) {
            // horizontal conv of the 4 incoming t rows -> hn[m] = h(yS-k+1+m)
            f2 hn[RB][2];
#pragma unroll
            for (int m = 0; m < RB; ++m) {
                const f2 t0 = tin[m][0], t1 = tin[m][1];
                float lft = __int_as_float(__builtin_amdgcn_ds_bpermute(a_up, __float_as_int(t1.y)));
                float rgt = __int_as_float(__builtin_amdgcn_ds_bpermute(a_dn, __float_as_int(t0.x)));
                lft = (lane == 0)  ? 0.f : lft;
                rgt = (lane == 63) ? 0.f : rgt;
                f2 tl0 = {lft,  t0.x};
                f2 mid = {t0.y, t1.x};
                f2 tr1 = {t1.y, rgt};
                hn[m][0] = pkfma(w1, t0, w0 * (tl0 + mid));
                hn[m][1] = pkfma(w1, t1, w0 * (mid + tr1));
            }

#pragma unroll
            for (int m = 0; m < RB; ++m) {
                const int r = yS - k + m;
                const bool rv = (unsigned)r < 256u;
#pragma unroll
                for (int i = 0; i < 2; ++i) {
                    f2 h_im1 = (m == 0) ? hA[k - 1][i] : (m == 1) ? hB[k - 1][i] : hn[m - 2][i];
                    f2 h_i   = (m == 0) ? hB[k - 1][i] : hn[m - 1][i];
                    // z = o[r] - lam*q  (BETA folded into tval/uval)
                    f2 z = pkfma(W0, h_im1 + hn[m][i],
                           pkfma(W1, h_i, orow[DEPTH - k + m][i]));
                    if (k < DEPTH) {
                        f2 t = tval(z);
                        tin[m][i] = rv ? t : zero;
                    } else {
                        tin[m][i] = uval(z);   // reuse tin as the u output
                    }
                }
            }

            // carries for next step: hA <- h(yS-k+3)=hn[2], hB <- hn[3]
#pragma unroll
            for (int i = 0; i < 2; ++i) {
                hA[k - 1][i] = hn[2][i];
                hB[k - 1][i] = hn[3][i];
            }
        }

        // ---- store u rows r = yS-10+m inside this strip ----
#pragma unroll
        for (int m = 0; m < RB; ++m) {
            const int r = yS - DEPTH + m;
            if (r >= y0 && r < y0 + ROWS) {
                f4 v;
                v.x = tin[m][0].x; v.y = tin[m][0].y;
                v.z = tin[m][1].x; v.w = tin[m][1].y;
                *reinterpret_cast<f4*>(up_lane + r * Ww) = v;
            }
        }
    }
}

extern "C" void kernel_launch(void* const* d_in, const int* in_sizes, int n_in,
                              void* d_out, int out_size, void* d_ws, size_t ws_size,
                              hipStream_t stream) {
    (void)in_sizes; (void)n_in; (void)out_size; (void)d_ws; (void)ws_size;
    const float* o     = (const float*)d_in[0];
    const float* sigma = (const float*)d_in[1];
    const float* lam   = (const float*)d_in[2];
    float* out = (float*)d_out;

    k_fused<<<PLANES * STRIPS, 64, 0, stream>>>(o, sigma, lam, out);
}